// Round 4
// baseline (156.818 us; speedup 1.0000x reference)
//
#include <hip/hip_runtime.h>
#include <hip/hip_bf16.h>

#define BATCH 2048
#define NNODES 512
#define HID 64
#define LN_EPS 1e-5f
#define NEG_SLOPE 0.01f

#define NTHREADS 256          // 4 waves
#define SUBS 4                // 16-row MFMA tiles per wave
#define ROWS 256              // 4 waves * 4 subs * 16 rows

typedef __attribute__((ext_vector_type(8))) short bf16x8;
typedef __attribute__((ext_vector_type(4))) float f32x4;

__device__ __forceinline__ short f2bf(float f) {
    union { __hip_bfloat16 h; short s; } u;
    u.h = __float2bfloat16(f);   // canonical RNE conversion (R3-verified)
    return u.s;
}

// Block = 1 node x 256 batch rows, 256 threads, NO LDS.
// Operand-swapped MFMA: acc = mfma(wf, af) so D is t^T relative to R3:
//   lane owns batch row (base + l16), hidden cols c*16 + lg*4 + i (f32x4).
// LN over hidden = in-register sum + shfl_xor {16,32}; f32x4 stores.
__global__ __launch_bounds__(NTHREADS) void wv_mfma2_kernel(
    const float* __restrict__ x,      // [B, N, H]
    const float* __restrict__ dec,    // [3, 4]
    const float* __restrict__ rec,    // [3, 4]
    const float* __restrict__ W,      // [N, H, H]
    const float* __restrict__ bias,   // [N, H]
    const float* __restrict__ gamma,  // [N, H]
    const float* __restrict__ beta,   // [N, H]
    const int*   __restrict__ scales, // [N]
    float* __restrict__ out)          // [B, N, H]
{
    const int tid  = threadIdx.x;
    const int wave = tid >> 6;
    const int lane = tid & 63;
    const int l16  = lane & 15;
    const int lg   = lane >> 4;      // 0..3

    const int node  = blockIdx.x >> 3;   // 0..511
    const int chunk = blockIdx.x & 7;    // 0..7
    const int b0    = chunk * ROWS;

    const int   sc   = scales[node];
    const float sfac = dec[sc * 4 + 1] + rec[sc * 4 + 1];

    // ---- W fragments (now the FIRST mfma operand): lane holds
    //      W[node][c*16+l16][s*32 + lg*8 + j]   (layout identical to R3)
    bf16x8 wf[4][2];
    const float* Wn = W + (size_t)node * HID * HID;
    #pragma unroll
    for (int c = 0; c < 4; ++c) {
        #pragma unroll
        for (int s = 0; s < 2; ++s) {
            const float* p = Wn + (c * 16 + l16) * HID + s * 32 + lg * 8;
            f32x4 w0 = *reinterpret_cast<const f32x4*>(p);
            f32x4 w1 = *reinterpret_cast<const f32x4*>(p + 4);
            bf16x8 f;
            f[0] = f2bf(w0[0]); f[1] = f2bf(w0[1]); f[2] = f2bf(w0[2]); f[3] = f2bf(w0[3]);
            f[4] = f2bf(w1[0]); f[5] = f2bf(w1[1]); f[6] = f2bf(w1[2]); f[7] = f2bf(w1[3]);
            wf[c][s] = f;
        }
    }

    // ---- per-lane epilogue params for cols c*16 + lg*4 .. +3
    f32x4 bb[4], gg[4], be[4];
    #pragma unroll
    for (int c = 0; c < 4; ++c) {
        const int pbase = node * HID + c * 16 + lg * 4;
        bb[c] = *reinterpret_cast<const f32x4*>(bias  + pbase);
        gg[c] = *reinterpret_cast<const f32x4*>(gamma + pbase);
        be[c] = *reinterpret_cast<const f32x4*>(beta  + pbase);
    }

    #pragma unroll
    for (int sub = 0; sub < SUBS; ++sub) {
        const int rl  = wave * (SUBS * 16) + sub * 16;   // local row base
        const int row = b0 + rl + l16;                   // this lane's batch row

        // ---- A-side x fragments (now the SECOND operand), layout as R3
        bf16x8 af[2];
        #pragma unroll
        for (int s = 0; s < 2; ++s) {
            const float* p = x + ((size_t)row * NNODES + node) * HID + s * 32 + lg * 8;
            f32x4 x0 = *reinterpret_cast<const f32x4*>(p);
            f32x4 x1 = *reinterpret_cast<const f32x4*>(p + 4);
            bf16x8 f;
            f[0] = f2bf(x0[0] * sfac); f[1] = f2bf(x0[1] * sfac);
            f[2] = f2bf(x0[2] * sfac); f[3] = f2bf(x0[3] * sfac);
            f[4] = f2bf(x1[0] * sfac); f[5] = f2bf(x1[1] * sfac);
            f[6] = f2bf(x1[2] * sfac); f[7] = f2bf(x1[3] * sfac);
            af[s] = f;
        }

        // ---- MFMA with swapped operands: lane -> (row = batch l16,
        //      cols = c*16 + lg*4 + i)
        f32x4 acc[4];
        #pragma unroll
        for (int c = 0; c < 4; ++c) {
            acc[c][0] = 0.f; acc[c][1] = 0.f; acc[c][2] = 0.f; acc[c][3] = 0.f;
            acc[c] = __builtin_amdgcn_mfma_f32_16x16x32_bf16(wf[c][0], af[0], acc[c], 0, 0, 0);
            acc[c] = __builtin_amdgcn_mfma_f32_16x16x32_bf16(wf[c][1], af[1], acc[c], 0, 0, 0);
        }

        // ---- epilogue, all in registers. t = acc + bias (in place).
        float pS = 0.f;
        #pragma unroll
        for (int c = 0; c < 4; ++c) {
            #pragma unroll
            for (int i = 0; i < 4; ++i) {
                acc[c][i] += bb[c][i];
                pS += acc[c][i];
            }
        }
        pS += __shfl_xor(pS, 16, 64);
        pS += __shfl_xor(pS, 32, 64);
        const float mu = pS * (1.0f / 64.0f);

        float qS = 0.f;
        #pragma unroll
        for (int c = 0; c < 4; ++c) {
            #pragma unroll
            for (int i = 0; i < 4; ++i) {
                const float d = acc[c][i] - mu;
                qS += d * d;
            }
        }
        qS += __shfl_xor(qS, 16, 64);
        qS += __shfl_xor(qS, 32, 64);
        const float var  = qS * (1.0f / 64.0f);
        const float rstd = 1.0f / sqrtf(var + LN_EPS);

        float* op = out + ((size_t)row * NNODES + node) * HID;
        #pragma unroll
        for (int c = 0; c < 4; ++c) {
            f32x4 o;
            #pragma unroll
            for (int i = 0; i < 4; ++i) {
                float v = (acc[c][i] - mu) * rstd * gg[c][i] + be[c][i];
                o[i] = v >= 0.f ? v : v * NEG_SLOPE;
            }
            *reinterpret_cast<f32x4*>(op + c * 16 + lg * 4) = o;
        }
    }
}

extern "C" void kernel_launch(void* const* d_in, const int* in_sizes, int n_in,
                              void* d_out, int out_size, void* d_ws, size_t ws_size,
                              hipStream_t stream) {
    const float* x      = (const float*)d_in[0];
    const float* dec    = (const float*)d_in[1];
    const float* rec    = (const float*)d_in[2];
    const float* W      = (const float*)d_in[3];
    const float* bias   = (const float*)d_in[4];
    const float* gamma  = (const float*)d_in[5];
    const float* beta   = (const float*)d_in[6];
    const int*   scales = (const int*)d_in[7];
    float* out = (float*)d_out;

    const int blocks = NNODES * (BATCH / ROWS);  // 512 * 8 = 4096
    wv_mfma2_kernel<<<blocks, NTHREADS, 0, stream>>>(
        x, dec, rec, W, bias, gamma, beta, scales, out);
}